// Round 4
// baseline (580.517 us; speedup 1.0000x reference)
//
#include <hip/hip_runtime.h>

// Problem constants: B=16, C=256, H=96, W=96, REP_K=3
#define B_    16
#define C_    256
#define HH    96
#define WW    96
#define W4    24            // WW/4 float4 columns
#define JT    48            // j-tile rows staged in LDS per pass (2 passes)
#define TYN   8             // h-groups
#define HPT   12            // h outputs per thread
#define TPB   (W4 * TYN)    // 192 threads = 3 waves

// Fused circular depthwise conv along H:
// out[b,c,h,w] = sum_j eff_w[c,(j-h)%96] * (x+meta_pe)[b,c,j,w] + bias[c]
// eff_w[c,k] = weight[c,k] + (k<3 ? rep_weight[c,k] : 0)
//
// One block per (b,c). The j-reduction is tiled: LDS holds a 48x96 slab
// (18.4 KB -> 8 blocks/CU for latency hiding) and we run two passes with a
// re-stage barrier. HPT=12 keeps the inner loop VALU-bound (24 CU-norm VALU
// cyc vs ~18 LDS cyc per wave-j) instead of LDS-bound (R2's HPT=6: 12 vs 18).
//
// R3 bug fixed here: the weight-window preload reads sWext entries written by
// OTHER threads, so it must sit behind a barrier. R3 preloaded with no barrier
// after the sWext writes -> race -> absmax 14.4.
__global__ __launch_bounds__(TPB, 6) void fused_circ_conv(
    const float* __restrict__ x,
    const float* __restrict__ meta_pe,
    const float* __restrict__ weight,
    const float* __restrict__ bias,
    const float* __restrict__ rep_weight,
    float* __restrict__ out)
{
    __shared__ float sX[JT * WW];     // 18 KB j-slab [j_local][w], meta_pe folded in
    __shared__ float sWext[2 * HH];   // eff_w doubled: sWext[t] = eff_w[t % 96]

    const int tid = threadIdx.x;
    const int blk = blockIdx.x;       // blk = b*256 + c
    const int c = blk & (C_ - 1);

    const size_t base = (size_t)blk * (HH * WW);
    const float4* __restrict__ xg4 = (const float4*)(x + base);
    const float* __restrict__ mp = meta_pe + c * HH;

    // --- stage effective weights (192 entries, one per thread) ---
    {
        int k = (tid < HH) ? tid : (tid - HH);
        float wv = weight[c * HH + k];
        if (k < 3) wv += rep_weight[c * 3 + k];
        sWext[tid] = wv;
    }
    __syncthreads();   // REQUIRED: win preload below reads other threads' sWext

    const int tx = tid % W4;      // w-quad
    const int ty = tid / W4;      // h-group
    const int h0 = ty * HPT;

    float4 acc[HPT];
#pragma unroll
    for (int i = 0; i < HPT; ++i) acc[i] = make_float4(0.f, 0.f, 0.f, 0.f);

    // Sliding window of 12 weights in registers (lives across the re-stage
    // barrier). Invariant: entering iteration j, win[(j-i) mod 12] ==
    // sWext[96 + (j-i) - h0] == eff_w[(j-(h0+i)) mod 96] for i in [1,12).
    float win[12];
#pragma unroll
    for (int t = 1; t < 12; ++t) win[t] = sWext[84 + t - h0];  // value for j = t-12

    const float4* __restrict__ xrow = (const float4*)sX + tx;
    const float* __restrict__ wrow = sWext + (96 - h0);
    float4* sX4 = (float4*)sX;

    for (int p = 0; p < 2; ++p) {
        // --- stage j-slab: rows p*48 .. p*48+47 (1152 float4 = 192 x 6) ---
        if (p) __syncthreads();       // all consumers of previous slab done
#pragma unroll
        for (int r = 0; r < 6; ++r) {
            int i = tid + TPB * r;               // slab-linear float4 index
            float4 v = xg4[p * (JT * W4) + i];   // global row p*48 + i/24
            float m = mp[p * JT + i / W4];
            v.x += m; v.y += m; v.z += m; v.w += m;
            sX4[i] = v;
        }
        __syncthreads();

        // --- reduce over this slab's j range ---
        for (int jj = p * JT; jj < p * JT + JT; jj += 12) {
#pragma unroll
            for (int r = 0; r < 12; ++r) {
                const int j = jj + r;            // j % 12 == r (jj multiple of 12)
                win[r] = wrow[j];                // new weight for this j
                float4 xv = xrow[(j - p * JT) * W4];  // X[j][4tx..], bcast over ty
#pragma unroll
                for (int i = 0; i < HPT; ++i) {
                    float wv = win[(r - i + 12) % 12];   // compile-time after unroll
                    acc[i].x += wv * xv.x;
                    acc[i].y += wv * xv.y;
                    acc[i].z += wv * xv.z;
                    acc[i].w += wv * xv.w;
                }
            }
        }
    }

    // --- epilogue: add bias, store coalesced ---
    const float bv = bias[c];
    float4* og4 = (float4*)(out + base);
#pragma unroll
    for (int i = 0; i < HPT; ++i) {
        float4 v = acc[i];
        v.x += bv; v.y += bv; v.z += bv; v.w += bv;
        og4[(h0 + i) * W4 + tx] = v;
    }
}

extern "C" void kernel_launch(void* const* d_in, const int* in_sizes, int n_in,
                              void* d_out, int out_size, void* d_ws, size_t ws_size,
                              hipStream_t stream) {
    const float* x          = (const float*)d_in[0];
    const float* meta_pe    = (const float*)d_in[1];
    const float* weight     = (const float*)d_in[2];
    const float* bias       = (const float*)d_in[3];
    const float* rep_weight = (const float*)d_in[4];
    float* out = (float*)d_out;

    fused_circ_conv<<<dim3(B_ * C_), dim3(TPB), 0, stream>>>(
        x, meta_pe, weight, bias, rep_weight, out);
}